// Round 1
// baseline (117.062 us; speedup 1.0000x reference)
//
#include <hip/hip_runtime.h>
#include <hip/hip_bf16.h>

// Problem: B=32, S=512, P=512, D=768
//   M = B*S = 16384 tokens, N = P = 512 prototypes, K = D = 768
// out[0 .. M*N)            = distances  ||x_m - p_n||^2
// out[M*N .. M*N + N*K)    = prototypes (fp32 passthrough)

#define M_TOK 16384
#define N_PROT 512
#define K_DIM 768

typedef __attribute__((ext_vector_type(4))) float f32x4;
typedef __attribute__((ext_vector_type(8))) short bf16x8;

typedef const __attribute__((address_space(1))) unsigned int g_uint;
typedef __attribute__((address_space(3))) unsigned int l_uint;

__device__ inline unsigned short f2bf(float f) {
    // round-to-nearest-even; inputs are finite Gaussians (no NaN/Inf handling needed)
    unsigned int u = __float_as_uint(f);
    u += 0x7fffu + ((u >> 16) & 1u);
    return (unsigned short)(u >> 16);
}

// One wave per 768-float row. Rows [0, M_TOK) come from inputs -> a_bf + x_sq.
// Rows [M_TOK, M_TOK+N_PROT) come from prototypes -> b_bf + p_sq + fp32 copy to out.
__global__ __launch_bounds__(256) void prep_kernel(
    const float* __restrict__ x, const float* __restrict__ p,
    unsigned short* __restrict__ a_bf, unsigned short* __restrict__ b_bf,
    float* __restrict__ x_sq, float* __restrict__ p_sq,
    float* __restrict__ proto_out)
{
    const int row  = blockIdx.x * 4 + (threadIdx.x >> 6);
    const int lane = threadIdx.x & 63;

    const float4* src4;
    unsigned short* dst;
    float4* pout4 = nullptr;
    if (row < M_TOK) {
        src4 = (const float4*)(x + (size_t)row * K_DIM);
        dst  = a_bf + (size_t)row * K_DIM;
    } else {
        const int r = row - M_TOK;
        src4  = (const float4*)(p + (size_t)r * K_DIM);
        dst   = b_bf + (size_t)r * K_DIM;
        pout4 = (float4*)(proto_out + (size_t)r * K_DIM);
    }

    float ssum = 0.0f;
#pragma unroll
    for (int j = 0; j < 3; ++j) {        // 192 float4 per row / 64 lanes
        const int idx = lane + j * 64;
        float4 v = src4[idx];
        ssum += v.x * v.x + v.y * v.y + v.z * v.z + v.w * v.w;
        ushort4 b;
        b.x = f2bf(v.x); b.y = f2bf(v.y); b.z = f2bf(v.z); b.w = f2bf(v.w);
        ((ushort4*)dst)[idx] = b;
        if (pout4) pout4[idx] = v;
    }

#pragma unroll
    for (int off = 32; off > 0; off >>= 1) ssum += __shfl_down(ssum, off);
    if (lane == 0) {
        if (row < M_TOK) x_sq[row] = ssum;
        else             p_sq[row - M_TOK] = ssum;
    }
}

// 128x128 block tile, BK=32, 4 waves in 2x2, each wave 64x64 via 4x4 mfma_f32_16x16x32_bf16.
// Staging: global_load_lds width 16 (wave-uniform LDS base + lane*16), row-major LDS, no pad.
// Epilogue: out[m][n] = x_sq[m] + p_sq[n] - 2*acc.
__global__ __launch_bounds__(256) void gemm_kernel(
    const unsigned short* __restrict__ A,   // [M,K] bf16
    const unsigned short* __restrict__ Bt,  // [N,K] bf16 (prototypes, row-major = B^T)
    const float* __restrict__ x_sq, const float* __restrict__ p_sq,
    float* __restrict__ out)                // [M,N] fp32
{
    __shared__ unsigned short lds_a[128 * 32];
    __shared__ unsigned short lds_b[128 * 32];

    const int tid  = threadIdx.x;
    const int wave = tid >> 6;
    const int lane = tid & 63;
    const int bm = blockIdx.y << 7;
    const int bn = blockIdx.x << 7;
    const int wm = (wave >> 1) << 6;   // wave row offset in block tile
    const int wn = (wave & 1) << 6;    // wave col offset
    const int quad = lane >> 4;        // 0..3
    const int l16  = lane & 15;

    // staging geometry: each wave stages 32 rows of A-tile and 32 rows of B-tile
    const int srow = wave * 32;
    const int lrow = lane >> 2;            // 0..15 (row within 16-row chunk)
    const int lcol = (lane & 3) * 8;       // ushort offset of this lane's 16B chunk

    const f32x4 zero = {0.0f, 0.0f, 0.0f, 0.0f};
    f32x4 acc[4][4];
#pragma unroll
    for (int mt = 0; mt < 4; ++mt)
#pragma unroll
        for (int nt = 0; nt < 4; ++nt) acc[mt][nt] = zero;

    for (int k0 = 0; k0 < K_DIM; k0 += 32) {
        __syncthreads();   // previous iteration's ds_reads complete before overwrite
#pragma unroll
        for (int i = 0; i < 2; ++i) {
            const unsigned short* ga =
                A + (size_t)(bm + srow + i * 16 + lrow) * K_DIM + k0 + lcol;
            __builtin_amdgcn_global_load_lds((g_uint*)ga,
                (l_uint*)&lds_a[(srow + i * 16) * 32], 16, 0, 0);
            const unsigned short* gb =
                Bt + (size_t)(bn + srow + i * 16 + lrow) * K_DIM + k0 + lcol;
            __builtin_amdgcn_global_load_lds((g_uint*)gb,
                (l_uint*)&lds_b[(srow + i * 16) * 32], 16, 0, 0);
        }
        __syncthreads();   // drains vmcnt(0): staged tile visible

        bf16x8 af[4], bfr[4];
#pragma unroll
        for (int mt = 0; mt < 4; ++mt)
            af[mt] = *(const bf16x8*)&lds_a[(wm + mt * 16 + l16) * 32 + quad * 8];
#pragma unroll
        for (int nt = 0; nt < 4; ++nt)
            bfr[nt] = *(const bf16x8*)&lds_b[(wn + nt * 16 + l16) * 32 + quad * 8];

#pragma unroll
        for (int mt = 0; mt < 4; ++mt)
#pragma unroll
            for (int nt = 0; nt < 4; ++nt)
                acc[mt][nt] = __builtin_amdgcn_mfma_f32_16x16x32_bf16(
                    af[mt], bfr[nt], acc[mt][nt], 0, 0, 0);
    }

    // Epilogue: C/D layout col = lane&15, row = quad*4 + i
    float ps[4];
#pragma unroll
    for (int nt = 0; nt < 4; ++nt) ps[nt] = p_sq[bn + wn + nt * 16 + l16];

#pragma unroll
    for (int mt = 0; mt < 4; ++mt) {
#pragma unroll
        for (int i = 0; i < 4; ++i) {
            const int gr = bm + wm + mt * 16 + quad * 4 + i;
            const float xs = x_sq[gr];
            float* orow = out + (size_t)gr * N_PROT + bn + wn + l16;
#pragma unroll
            for (int nt = 0; nt < 4; ++nt)
                orow[nt * 16] = xs + ps[nt] - 2.0f * acc[mt][nt][i];
        }
    }
}

extern "C" void kernel_launch(void* const* d_in, const int* in_sizes, int n_in,
                              void* d_out, int out_size, void* d_ws, size_t ws_size,
                              hipStream_t stream) {
    const float* inputs = (const float*)d_in[0];   // [32,512,768] fp32
    const float* protos = (const float*)d_in[1];   // [512,768]    fp32
    float* out = (float*)d_out;

    // workspace layout (all 16B-aligned):
    //   a_bf : M*K bf16 = 25,165,824 B
    //   b_bf : N*K bf16 =    786,432 B
    //   x_sq : M fp32   =     65,536 B
    //   p_sq : N fp32   =      2,048 B
    char* ws = (char*)d_ws;
    unsigned short* a_bf = (unsigned short*)ws;
    unsigned short* b_bf = (unsigned short*)(ws + 25165824);
    float* x_sq = (float*)(ws + 25165824 + 786432);
    float* p_sq = (float*)(ws + 25165824 + 786432 + 65536);
    float* proto_out = out + (size_t)M_TOK * N_PROT;   // second tuple element

    // 16896 rows / 4 rows-per-block
    prep_kernel<<<4224, 256, 0, stream>>>(inputs, protos, a_bf, b_bf, x_sq, p_sq, proto_out);

    dim3 grid(N_PROT / 128, M_TOK / 128);   // (4, 128)
    gemm_kernel<<<grid, 256, 0, stream>>>(a_bf, b_bf, x_sq, p_sq, out);
}